// Round 8
// baseline (187.822 us; speedup 1.0000x reference)
//
#include <hip/hip_runtime.h>
#include <math.h>

namespace {

constexpr int kB    = 16384;
constexpr int kS0   = 7;
constexpr int kS1   = 7;
constexpr int kD    = 30;
constexpr int kCells = kB * kS0 * kS1;   // 802816
constexpr int TPB   = 256;
constexpr int T     = 4;                 // tiles per block (pipelined)
constexpr int NBLK  = kCells / (TPB * T);// 784 (exact: 784*4*256 = 802816)
constexpr int NSLOT = 64;                // spread-atomic partial slots
constexpr float kInv7 = 1.0f / 7.0f;
constexpr float kWC = 5.0f;
constexpr float kWN = 0.5f;

__device__ __forceinline__ float frcp(float x) {
    return __builtin_amdgcn_rcpf(x);     // 1-instr v_rcp_f32; ~1e-7 rel err,
}                                        // output tolerance is 2% -> free

__device__ __forceinline__ float sigm(float x) {
    return frcp(1.0f + __expf(-x));
}

// Per-cell loss given the tile staged in LDS.
__device__ __forceinline__ float cell_loss(const float* __restrict__ sp, int tid,
                                           int cell, float4 tb4, int g, int tc)
{
    float f[kD];
    {
        const float2* p2 = reinterpret_cast<const float2*>(sp + tid * kD);
        #pragma unroll
        for (int q = 0; q < kD / 2; ++q) {
            float2 t = p2[q];
            f[2 * q]     = t.x;
            f[2 * q + 1] = t.y;
        }
    }

    const int cj = cell % kS1;            // column -> xg
    const int ci = (cell / kS1) % kS0;    // row    -> yg
    const float tox = tb4.x, toy = tb4.y, tw = tb4.z, th = tb4.w;

    const float conf0 = sigm(f[0]);
    const float conf1 = sigm(f[1]);
    float pbx[2], pby[2], pbw[2], pbh[2];
    #pragma unroll
    for (int k = 0; k < 2; ++k) {
        pbx[k] = sigm(f[2 + 4 * k + 0]);
        pby[k] = sigm(f[2 + 4 * k + 1]);
        pbw[k] = sigm(f[2 + 4 * k + 2]);
        pbh[k] = sigm(f[2 + 4 * k + 3]);
    }

    // softmax over 20 classes, NO max-subtraction: inputs ~N(0,1), |x|<~6,
    // exp<=403, 20-term sum far from fp32 overflow. Only value at tc needed.
    float csum = 0.0f, et = 0.0f;
    #pragma unroll
    for (int q = 0; q < 20; ++q) {
        const float e = __expf(f[10 + q]);
        csum += e;
        et = (q == tc) ? e : et;          // constant q -> cndmask
    }
    const float cls_t = et * frcp(csum);

    const float x = (float)cj, y = (float)ci;
    const float tcx = (x + tox) * kInv7;
    const float tcy = (y + toy) * kInv7;
    const float thw = tw * 0.5f, thh = th * 0.5f;
    const float tarea = tw * th;

    float iou[2];
    #pragma unroll
    for (int k = 0; k < 2; ++k) {
        const float pcx = (x + pbx[k]) * kInv7;
        const float pcy = (y + pby[k]) * kInv7;
        const float pw = pbw[k], ph = pbh[k];
        const float tb_ = fminf(tcx + thw, pcx + pw * 0.5f) - fmaxf(tcx - thw, pcx - pw * 0.5f);
        const float lr_ = fminf(tcy + thh, pcy + ph * 0.5f) - fmaxf(tcy - thh, pcy - ph * 0.5f);
        float inter = tb_ * lr_;
        inter = (tb_ < 0.0f || lr_ < 0.0f) ? 0.0f : inter;
        iou[k] = inter * frcp(tarea + pw * ph - inter);
    }

    const bool b1 = (iou[1] > iou[0]);     // tie -> box 0 (first-max)
    const float bx = b1 ? pbx[1] : pbx[0];
    const float by = b1 ? pby[1] : pby[0];
    const float bw = b1 ? pbw[1] : pbw[0];
    const float bh = b1 ? pbh[1] : pbh[0];
    const float conf_b = b1 ? conf1 : conf0;
    const float iou_b  = b1 ? iou[1] : iou[0];

    const float dx = bx - tox;
    const float dy = by - toy;
    const float dw = sqrtf(bw) - sqrtf(tw);
    const float dh = sqrtf(bh) - sqrtf(th);
    const float coord = dx * dx + dy * dy + dw * dw + dh * dh;
    const float d1 = conf_b - iou_b;
    const float d2 = 1.0f - cls_t;
    const float obj   = kWC * coord + d1 * d1 + d2 * d2;
    const float noobj = kWN * (conf0 * conf0 + conf1 * conf1);

    return (g == 1) ? obj : noobj;
}

// launch_bounds(256,4): VGPR cap 128 — the prefetch pipeline needs ~90 live.
// (r1/r5/r6 showed the default allocator register-minimizes to 28-48 and
// serializes the load batch; r4 showed cap-48 spills the prefetch.)
__global__ void __launch_bounds__(TPB, 4) yolo_loss_kernel(
    const float* __restrict__ pred,
    const int*   __restrict__ grid,
    const float* __restrict__ tbox,
    const int*   __restrict__ tcls,
    float* __restrict__ partials)   // 64 f32 slots in d_ws, pre-zeroed
{
    __shared__ float sp[TPB * kD];        // 30720 B, one tile
    __shared__ float wsum[TPB / 64];

    const int tid   = threadIdx.x;
    const int wave  = tid >> 6;
    const int lane  = tid & 63;
    const int tile0 = blockIdx.x * T;
    const int etid  = 1792 + (tid & 127); // benign-race ragged tail (r7)

    float4* s4 = reinterpret_cast<float4*>(sp);
    const float4* __restrict__ tb4p = reinterpret_cast<const float4*>(tbox);

    // --- prologue: prefetch tile 0 ---
    float4 r[8]; float4 tb; int gg, tc;
    {
        const float4* g4 = reinterpret_cast<const float4*>(
            pred + (size_t)tile0 * TPB * kD);
        #pragma unroll
        for (int k = 0; k < 7; ++k) r[k] = g4[tid + 256 * k];
        r[7] = g4[etid];
        const int c = tile0 * TPB + tid;
        tb = tb4p[c]; gg = grid[c]; tc = tcls[c];
        __builtin_amdgcn_sched_barrier(0);
    }
    #pragma unroll
    for (int k = 0; k < 7; ++k) s4[tid + 256 * k] = r[k];
    s4[etid] = r[7];
    __syncthreads();

    // --- pipelined main loop: issue tile t+1 loads, compute tile t, then
    // stage t+1 into LDS. Loads stay in flight UNDER the compute; the
    // barrier's vmcnt drain lands exactly where the data is needed. ---
    float v = 0.0f;
    #pragma unroll
    for (int t = 0; t < T; ++t) {
        const int cell = (tile0 + t) * TPB + tid;

        float4 rn[8]; float4 tbn; int gn, tcn;
        if (t + 1 < T) {
            const float4* g4n = reinterpret_cast<const float4*>(
                pred + (size_t)(tile0 + t + 1) * TPB * kD);
            #pragma unroll
            for (int k = 0; k < 7; ++k) rn[k] = g4n[tid + 256 * k];
            rn[7] = g4n[etid];
            tbn = tb4p[cell + TPB]; gn = grid[cell + TPB]; tcn = tcls[cell + TPB];
            __builtin_amdgcn_sched_barrier(0);   // loads issue BEFORE compute
        }

        v += cell_loss(sp, tid, cell, tb, gg, tc);

        if (t + 1 < T) {
            __syncthreads();                     // all LDS reads of tile t done
            #pragma unroll
            for (int k = 0; k < 7; ++k) s4[tid + 256 * k] = rn[k];
            s4[etid] = rn[7];
            __syncthreads();                     // tile t+1 visible
            tb = tbn; gg = gn; tc = tcn;
        }
    }

    // --- wave64 shuffle reduce, cross-wave via LDS, one spread atomic ---
    #pragma unroll
    for (int off = 32; off > 0; off >>= 1) v += __shfl_down(v, off, 64);
    if (lane == 0) wsum[wave] = v;
    __syncthreads();
    if (tid == 0) {
        atomicAdd(&partials[blockIdx.x & (NSLOT - 1)],
                  wsum[0] + wsum[1] + wsum[2] + wsum[3]);
    }
}

__global__ void finish_kernel(const float* __restrict__ partials,
                              float* __restrict__ out)
{
    float v = partials[threadIdx.x];      // 64 threads = 1 wave
    #pragma unroll
    for (int off = 32; off > 0; off >>= 1) v += __shfl_down(v, off, 64);
    if (threadIdx.x == 0) out[0] = v * (1.0f / kB);
}

} // namespace

extern "C" void kernel_launch(void* const* d_in, const int* in_sizes, int n_in,
                              void* d_out, int out_size, void* d_ws, size_t ws_size,
                              hipStream_t stream) {
    const float* pred = (const float*)d_in[0];
    const int*   grid = (const int*)d_in[1];
    const float* tbox = (const float*)d_in[2];
    const int*   tcls = (const int*)d_in[3];
    float* out      = (float*)d_out;
    float* partials = (float*)d_ws;       // 64 f32, poisoned -> zero each call

    hipMemsetAsync(partials, 0, NSLOT * sizeof(float), stream);
    yolo_loss_kernel<<<NBLK, TPB, 0, stream>>>(pred, grid, tbox, tcls, partials);
    finish_kernel<<<1, 64, 0, stream>>>(partials, out);
}

// Round 9
// 160.965 us; speedup vs baseline: 1.1668x; 1.1668x over previous
//
#include <hip/hip_runtime.h>
#include <math.h>

namespace {

constexpr int kB    = 16384;
constexpr int kS0   = 7;
constexpr int kS1   = 7;
constexpr int kD    = 30;
constexpr int kCells = kB * kS0 * kS1;   // 802816
constexpr int TPB   = 256;
constexpr int NBLK  = kCells / TPB;      // 3136 (exact)
constexpr float kInv7 = 1.0f / 7.0f;
constexpr float kWC = 5.0f;
constexpr float kWN = 0.5f;

__device__ __forceinline__ float frcp(float x) {
    return __builtin_amdgcn_rcpf(x);     // v_rcp_f32: ~1e-7 rel err; output
}                                        // tolerance is 2% -> free accuracy

__device__ __forceinline__ float sigm(float x) {
    return frcp(1.0f + __expf(-x));
}

// Flat r7 skeleton (best measured; never spilled). launch_bounds(256,4):
// VGPR cap 128 so the 8-float4 load batch can live in registers (default
// allocator minimized to 28-48 and serialized it -> r1/r5/r6).
// NO register prefetch across barriers: r4/r5/r8 proved the allocator spills
// it to scratch (WRITE_SIZE 44-68 MB) every time.
__global__ void __launch_bounds__(TPB, 4) yolo_loss_kernel(
    const float* __restrict__ pred,
    const int*   __restrict__ grid,
    const float* __restrict__ tbox,
    const int*   __restrict__ tcls,
    float* __restrict__ partials)   // NBLK f32 slots in d_ws (all overwritten)
{
    __shared__ float sp[TPB * kD];        // 30720 B staging for pred tile
    __shared__ float wsum[TPB / 64];

    const int tid   = threadIdx.x;
    const int cell0 = blockIdx.x * TPB;
    const int cell  = cell0 + tid;
    const int wave  = tid >> 6;
    const int lane  = tid & 63;

    // --- coalesced load batch: 1920 float4 = 256*7 + 128; branchless ragged
    // tail (threads 128..255 redundantly load/store identical data: benign).
    const float4* __restrict__ g4 =
        reinterpret_cast<const float4*>(pred + (size_t)cell0 * kD);
    float4* s4 = reinterpret_cast<float4*>(sp);
    const int etid = 1792 + (tid & 127);

    float4 r[8];
    #pragma unroll
    for (int k = 0; k < 7; ++k) r[k] = g4[tid + 256 * k];
    r[7] = g4[etid];

    const float4 tb4 = reinterpret_cast<const float4*>(tbox)[cell];
    const int g  = grid[cell];
    const int tc = tcls[cell];

    // all 11 global loads issued before the first ds_write (MLP ~11)
    __builtin_amdgcn_sched_barrier(0);

    #pragma unroll
    for (int k = 0; k < 7; ++k) s4[tid + 256 * k] = r[k];
    s4[etid] = r[7];
    __syncthreads();

    const int cj = cell % kS1;            // column -> xg
    const int ci = (cell / kS1) % kS0;    // row    -> yg

    // --- per-cell 30 floats from LDS. Batch ALL 15 ds_read2_b32 before any
    // use (same sched_barrier trick as the global batch): kills the
    // read->use->read latency chains a lean VGPR allocation produces.
    float f[kD];
    {
        const float2* p2 = reinterpret_cast<const float2*>(sp + tid * kD);
        #pragma unroll
        for (int q = 0; q < kD / 2; ++q) {
            float2 t = p2[q];
            f[2 * q]     = t.x;
            f[2 * q + 1] = t.y;
        }
        __builtin_amdgcn_sched_barrier(0);
    }

    const float tox = tb4.x, toy = tb4.y, tw = tb4.z, th = tb4.w;

    const float conf0 = sigm(f[0]);
    const float conf1 = sigm(f[1]);
    float pbx[2], pby[2], pbw[2], pbh[2];
    #pragma unroll
    for (int k = 0; k < 2; ++k) {
        pbx[k] = sigm(f[2 + 4 * k + 0]);
        pby[k] = sigm(f[2 + 4 * k + 1]);
        pbw[k] = sigm(f[2 + 4 * k + 2]);
        pbh[k] = sigm(f[2 + 4 * k + 3]);
    }

    // --- softmax over 20 classes, no max-subtraction: inputs ~N(0,1), so
    // exp <= ~e^6 and a 20-term fp32 sum is nowhere near overflow. Only the
    // value at tc is needed.
    float csum = 0.0f, et = 0.0f;
    #pragma unroll
    for (int q = 0; q < 20; ++q) {
        const float e = __expf(f[10 + q]);
        csum += e;
        et = (q == tc) ? e : et;          // constant q -> cndmask
    }
    const float cls_t = et * frcp(csum);

    // --- IOU of both predicted boxes vs target box ---
    const float x = (float)cj, y = (float)ci;
    const float tcx = (x + tox) * kInv7;
    const float tcy = (y + toy) * kInv7;
    const float thw = tw * 0.5f, thh = th * 0.5f;
    const float tarea = tw * th;

    float iou[2];
    #pragma unroll
    for (int k = 0; k < 2; ++k) {
        const float pcx = (x + pbx[k]) * kInv7;
        const float pcy = (y + pby[k]) * kInv7;
        const float pw = pbw[k], ph = pbh[k];
        const float tb_ = fminf(tcx + thw, pcx + pw * 0.5f) - fmaxf(tcx - thw, pcx - pw * 0.5f);
        const float lr_ = fminf(tcy + thh, pcy + ph * 0.5f) - fmaxf(tcy - thh, pcy - ph * 0.5f);
        float inter = tb_ * lr_;
        inter = (tb_ < 0.0f || lr_ < 0.0f) ? 0.0f : inter;
        iou[k] = inter * frcp(tarea + pw * ph - inter);
    }

    const bool b1 = (iou[1] > iou[0]);     // tie -> box 0 (first-max)
    const float bx = b1 ? pbx[1] : pbx[0];
    const float by = b1 ? pby[1] : pby[0];
    const float bw = b1 ? pbw[1] : pbw[0];
    const float bh = b1 ? pbh[1] : pbh[0];
    const float conf_b = b1 ? conf1 : conf0;
    const float iou_b  = b1 ? iou[1] : iou[0];

    const float dx = bx - tox;
    const float dy = by - toy;
    const float dw = sqrtf(bw) - sqrtf(tw);
    const float dh = sqrtf(bh) - sqrtf(th);
    const float coord = dx * dx + dy * dy + dw * dw + dh * dh;
    const float d1 = conf_b - iou_b;
    const float d2 = 1.0f - cls_t;
    const float obj   = kWC * coord + d1 * d1 + d2 * d2;
    const float noobj = kWN * (conf0 * conf0 + conf1 * conf1);

    float v = (g == 1) ? obj : noobj;

    // --- wave64 shuffle reduce, cross-wave via LDS, then a PLAIN STORE of
    // the block partial (no atomics at all; every slot overwritten every
    // call, so the 0xAA ws-poison needs no zeroing dispatch either).
    #pragma unroll
    for (int off = 32; off > 0; off >>= 1) v += __shfl_down(v, off, 64);
    if (lane == 0) wsum[wave] = v;
    __syncthreads();
    if (tid == 0) {
        partials[blockIdx.x] = wsum[0] + wsum[1] + wsum[2] + wsum[3];
    }
}

__global__ void __launch_bounds__(256) finish_kernel(
    const float* __restrict__ partials, float* __restrict__ out)
{
    __shared__ float wsum[4];
    const int tid = threadIdx.x;
    float v = 0.0f;
    for (int i = tid; i < NBLK; i += 256) v += partials[i];  // 13 iters
    #pragma unroll
    for (int off = 32; off > 0; off >>= 1) v += __shfl_down(v, off, 64);
    if ((tid & 63) == 0) wsum[tid >> 6] = v;
    __syncthreads();
    if (tid == 0) out[0] = (wsum[0] + wsum[1] + wsum[2] + wsum[3]) * (1.0f / kB);
}

} // namespace

extern "C" void kernel_launch(void* const* d_in, const int* in_sizes, int n_in,
                              void* d_out, int out_size, void* d_ws, size_t ws_size,
                              hipStream_t stream) {
    const float* pred = (const float*)d_in[0];
    const int*   grid = (const int*)d_in[1];
    const float* tbox = (const float*)d_in[2];
    const int*   tcls = (const int*)d_in[3];
    float* out      = (float*)d_out;
    float* partials = (float*)d_ws;       // NBLK f32; fully overwritten

    yolo_loss_kernel<<<NBLK, TPB, 0, stream>>>(pred, grid, tbox, tcls, partials);
    finish_kernel<<<1, 256, 0, stream>>>(partials, out);
}